// Round 10
// baseline (49.414 us; speedup 1.0000x reference)
//
#include <hip/hip_runtime.h>
#include <hip/hip_fp16.h>
#include <math.h>

#define NUM_CLASSES 80
#define M_GT 128

__device__ __forceinline__ float focal_neg(float x) {
    // (1-ALPHA)=0.75, t=0 term: 0.75 * p^2 * (max(x,0)+log1p(exp(-|x|)))
    float ax = fabsf(x);
    float e  = __expf(-ax);
    float s  = 1.f + e;
    float r  = __builtin_amdgcn_rcpf(s);
    float l1p = __logf(s);
    float ce0 = fmaxf(x, 0.f) + l1p;
    float pr  = (x >= 0.f) ? r : e * r;      // sigmoid(x)
    return 0.75f * pr * pr * ce0;
}

__device__ __forceinline__ float focal_target_corr(float x) {
    // replace t=0 term with t=1 term for the target class
    float ax = fabsf(x);
    float e  = __expf(-ax);
    float s  = 1.f + e;
    float r  = __builtin_amdgcn_rcpf(s);
    float l1p = __logf(s);
    float ce0 = fmaxf(x, 0.f) + l1p;
    float pr  = (x >= 0.f) ? r : e * r;
    float om  = 1.f - pr;
    return 0.25f * om * om * (ce0 - x) - 0.75f * pr * pr * ce0;
}

// pack two non-negative floats as fp16 bit-patterns into one u32 (y in high lane)
__device__ __forceinline__ unsigned pack_rd(float x, float y) {
    return ((unsigned)__half_as_ushort(__float2half_rd(y)) << 16) |
           (unsigned)__half_as_ushort(__float2half_rd(x));
}
__device__ __forceinline__ unsigned pack_ru(float x, float y) {
    return ((unsigned)__half_as_ushort(__float2half_ru(y)) << 16) |
           (unsigned)__half_as_ushort(__float2half_ru(x));
}

__global__ __launch_bounds__(256) void yolo_fused_kernel(
    const float* __restrict__ box_preds,   // [B,N,4]
    const float* __restrict__ cls_preds,   // [B,N,C]
    const float* __restrict__ gt_boxes,    // [B,M,4]
    const int*   __restrict__ gt_labels,   // [B,M]
    float4* __restrict__ partials,         // [nb] per-block {box,cls,npos,-}
    int* __restrict__ done_cnt,            // zeroed via hipMemsetAsync each launch
    float* __restrict__ out,
    int N, int nb)
{
    const int b    = blockIdx.y;
    const int tid  = threadIdx.x;
    const int n    = blockIdx.x * 256 + tid;
    const int lane = tid & 63;
    const int wave = tid >> 6;
    const int bid  = blockIdx.y * gridDim.x + blockIdx.x;

    __shared__ float4   sgt[M_GT];
    __shared__ uint2    spk[M_GT];     // conservative fp16 bits: {lo=(y1,x1)_rd, hi=(y2,x2)_ru}
    __shared__ int      slbl[M_GT];
    __shared__ int      s_cnt;
    __shared__ bool     s_last;
    __shared__ unsigned plist[256];
    __shared__ float    redb[4], redc[4];

    if (tid == 0) { s_cnt = 0; s_last = false; }
    if (tid < M_GT) {
        float4 g = reinterpret_cast<const float4*>(gt_boxes + (size_t)b * M_GT * 4)[tid];
        sgt[tid]  = g;
        slbl[tid] = gt_labels[b * M_GT + tid];
        uint2 pk;
        pk.x = pack_rd(g.x, g.y);              // lo corner rounded down
        pk.y = pack_ru(g.z, g.w) | 0x80008000u; // hi corner rounded up, bias pre-OR'd
        spk[tid] = pk;
    }
    __syncthreads();

    const int nld = (n < N) ? n : (N - 1);
    float4 p = reinterpret_cast<const float4*>(box_preds + (size_t)b * N * 4)[nld];
    const float aw = p.z - p.x, ah = p.w - p.y, a1 = aw * ah;

    const unsigned P_lo     = pack_rd(p.x, p.y);
    const unsigned P_hi_or  = pack_ru(p.z, p.w) | 0x80008000u;

    // ---- pass 1: conservative overlap masks, 2 GTs per ds_read_b128 ----
    // overlap superset test: px2>=gx1 & gx2>=px1 & py2>=gy1 & gy2>=py1, on fp16 bit
    // patterns (all coords >= 0 so unsigned bit order == value order). Per-u16-lane
    // "a>=b" flag = bit15 of (0x8000+a-b); no borrow crosses lanes since values <0x8000.
    const uint4* spk4 = reinterpret_cast<const uint4*>(spk);
    unsigned mk[4];
    #pragma unroll
    for (int q = 0; q < 4; ++q) {
        unsigned mm = 0;
        #pragma unroll
        for (int i = 0; i < 16; ++i) {
            uint4 w4 = spk4[q * 16 + i];      // {g0.lo, g0.hi|bias, g1.lo, g1.hi|bias}
            unsigned c0 = (P_hi_or - w4.x) & (w4.y - P_lo);
            unsigned c1 = (P_hi_or - w4.z) & (w4.w - P_lo);
            if ((c0 & 0x80008000u) == 0x80008000u) mm |= (1u << (2 * i));
            if ((c1 & 0x80008000u) == 0x80008000u) mm |= (1u << (2 * i + 1));
        }
        mk[q] = mm;
    }

    // ---- pass 2: exact fp32 GIoU over candidates (ascending order -> first-max kept) ----
    float best = -1e30f;   // tracks gip = giou + 1
    int   bidx = 0;
    #pragma unroll
    for (int q = 0; q < 4; ++q) {
        unsigned mm = mk[q];
        while (mm) {
            int t = __ffs(mm) - 1;
            mm &= mm - 1;
            int m = q * 32 + t;
            float4 g = sgt[m];
            float gw = g.z - g.x, gh = g.w - g.y, gA = gw * gh;
            float dx = fminf(p.z, g.z) - fmaxf(p.x, g.x);
            float dy = fminf(p.w, g.w) - fmaxf(p.y, g.y);
            float ex = (aw + gw) - dx;            // enclosure extents (identity, unclamped dx)
            float ey = (ah + gh) - dy;
            float inter = fmaxf(dx, 0.f) * fmaxf(dy, 0.f);   // clamp: mask may be dilated
            float uni = (a1 + gA) - inter;
            float ae  = ex * ey;
            // giou + 1 = (inter*ae + uni^2) / (uni*ae) — single reciprocal
            float gip = fmaf(uni, uni, inter * ae) * __builtin_amdgcn_rcpf(uni * ae);
            if (gip > best) { best = gip; bidx = m; }   // strict > keeps first idx
        }
    }
    // Exactness: positives (giou>0.3) have inter>0 with their argmax GT; the conservative
    // mask is a superset of overlapping GTs; dilation-extras have inter=0 -> gip<=1<1.3.

    bool  pos   = (n < N) && (best > 1.3f);     // giou > 0.3
    float box_l = pos ? (2.f - best) : 0.f;     // 1 - giou (elementwise giou == best)

    // ---- block-level compaction of positives ----
    {
        unsigned long long mkb = __ballot(pos);
        int cw = __popcll(mkb);
        if (cw > 0) {
            int leader = __ffsll(mkb) - 1;
            int base = 0;
            if (lane == leader) base = atomicAdd(&s_cnt, cw);   // LDS atomic
            base = __shfl(base, leader);
            if (pos) {
                int pre = __popcll(mkb & ((1ull << lane) - 1ull));
                plist[base + pre] = ((unsigned)slbl[bidx] << 18) | (unsigned)(b * N + n);
            }
        }
    }
    __syncthreads();

    // ---- focal over compacted positives (~17/block avg) ----
    const int cnt = s_cnt;
    float cls_l = 0.f;
    for (int i = tid; i < cnt; i += 256) {
        unsigned u = plist[i];
        int row = (int)(u & 0x3FFFFu);
        int lbl = (int)(u >> 18);
        const float* xrow = cls_preds + (size_t)row * NUM_CLASSES;
        float cl = 0.f;
        #pragma unroll 5
        for (int c4 = 0; c4 < NUM_CLASSES / 4; ++c4) {
            float4 xv = reinterpret_cast<const float4*>(xrow)[c4];
            cl += focal_neg(xv.x);
            cl += focal_neg(xv.y);
            cl += focal_neg(xv.z);
            cl += focal_neg(xv.w);
        }
        cl += focal_target_corr(xrow[lbl]);
        cls_l += cl;
    }

    // ---- block reduction ----
    #pragma unroll
    for (int off = 32; off > 0; off >>= 1) {
        box_l += __shfl_down(box_l, off);
        cls_l += __shfl_down(cls_l, off);
    }
    if (lane == 0) { redb[wave] = box_l; redc[wave] = cls_l; }
    __syncthreads();

    // ---- publish partials (agent-scope) + last-block-done final reduce ----
    if (tid == 0) {
        float b0 = redb[0] + redb[1] + redb[2] + redb[3];
        float c0 = redc[0] + redc[1] + redc[2] + redc[3];
        float* slot = (float*)&partials[bid];
        __hip_atomic_store(slot + 0, b0, __ATOMIC_RELAXED, __HIP_MEMORY_SCOPE_AGENT);
        __hip_atomic_store(slot + 1, c0, __ATOMIC_RELAXED, __HIP_MEMORY_SCOPE_AGENT);
        __hip_atomic_store(slot + 2, (float)cnt, __ATOMIC_RELAXED, __HIP_MEMORY_SCOPE_AGENT);
        int old = __hip_atomic_fetch_add(done_cnt, 1, __ATOMIC_ACQ_REL,
                                         __HIP_MEMORY_SCOPE_AGENT);
        s_last = (old == nb - 1);
    }
    __syncthreads();

    if (s_last) {
        const float* base = (const float*)partials;
        double sb = 0.0, sc = 0.0, sp = 0.0;
        for (int i = tid; i < nb; i += 256) {
            sb += (double)__hip_atomic_load(base + 4 * i + 0, __ATOMIC_RELAXED,
                                            __HIP_MEMORY_SCOPE_AGENT);
            sc += (double)__hip_atomic_load(base + 4 * i + 1, __ATOMIC_RELAXED,
                                            __HIP_MEMORY_SCOPE_AGENT);
            sp += (double)__hip_atomic_load(base + 4 * i + 2, __ATOMIC_RELAXED,
                                            __HIP_MEMORY_SCOPE_AGENT);
        }
        #pragma unroll
        for (int off = 32; off > 0; off >>= 1) {
            sb += __shfl_down(sb, off);
            sc += __shfl_down(sc, off);
            sp += __shfl_down(sp, off);
        }
        __shared__ double rb[4], rc[4], rp[4];
        if (lane == 0) { rb[wave] = sb; rc[wave] = sc; rp[wave] = sp; }
        __syncthreads();
        if (tid == 0) {
            double B0 = rb[0] + rb[1] + rb[2] + rb[3];
            double C0 = rc[0] + rc[1] + rc[2] + rc[3];
            double P0 = rp[0] + rp[1] + rp[2] + rp[3];
            out[0] = (float)((5.0 * B0 + C0) / fmax(P0, 1.0));
        }
    }
}

extern "C" void kernel_launch(void* const* d_in, const int* in_sizes, int n_in,
                              void* d_out, int out_size, void* d_ws, size_t ws_size,
                              hipStream_t stream) {
    const float* box_preds = (const float*)d_in[0];
    const float* cls_preds = (const float*)d_in[1];
    const float* gt_boxes  = (const float*)d_in[2];
    const int*   gt_labels = (const int*)d_in[3];

    const int B = in_sizes[3] / M_GT;            // gt_labels is [B,M]
    const int N = in_sizes[0] / (4 * B);         // box_preds is [B,N,4]

    int*    done_cnt = (int*)d_ws;
    float4* partials = (float4*)((char*)d_ws + 16);
    float*  out      = (float*)d_out;

    const int gx = (N + 255) / 256;
    const int nb = gx * B;

    (void)hipMemsetAsync(done_cnt, 0, sizeof(int), stream);   // graph-safe node

    dim3 grid(gx, B);
    yolo_fused_kernel<<<grid, 256, 0, stream>>>(box_preds, cls_preds, gt_boxes,
                                                gt_labels, partials, done_cnt,
                                                out, N, nb);
}

// Round 11
// 29.253 us; speedup vs baseline: 1.6892x; 1.6892x over previous
//
#include <hip/hip_runtime.h>
#include <hip/hip_fp16.h>
#include <math.h>

#define NUM_CLASSES 80
#define M_GT 128

__device__ __forceinline__ float focal_neg(float x) {
    // (1-ALPHA)=0.75, t=0 term: 0.75 * p^2 * (max(x,0)+log1p(exp(-|x|)))
    float ax = fabsf(x);
    float e  = __expf(-ax);
    float s  = 1.f + e;
    float r  = __builtin_amdgcn_rcpf(s);
    float l1p = __logf(s);
    float ce0 = fmaxf(x, 0.f) + l1p;
    float pr  = (x >= 0.f) ? r : e * r;      // sigmoid(x)
    return 0.75f * pr * pr * ce0;
}

__device__ __forceinline__ float focal_target_corr(float x) {
    // replace t=0 term with t=1 term for the target class
    float ax = fabsf(x);
    float e  = __expf(-ax);
    float s  = 1.f + e;
    float r  = __builtin_amdgcn_rcpf(s);
    float l1p = __logf(s);
    float ce0 = fmaxf(x, 0.f) + l1p;
    float pr  = (x >= 0.f) ? r : e * r;
    float om  = 1.f - pr;
    return 0.25f * om * om * (ce0 - x) - 0.75f * pr * pr * ce0;
}

// pack two non-negative floats as fp16 bit-patterns into one u32 (y in high half)
__device__ __forceinline__ unsigned pack_rd(float x, float y) {
    return ((unsigned)__half_as_ushort(__float2half_rd(y)) << 16) |
           (unsigned)__half_as_ushort(__float2half_rd(x));
}
__device__ __forceinline__ unsigned pack_ru(float x, float y) {
    return ((unsigned)__half_as_ushort(__float2half_ru(y)) << 16) |
           (unsigned)__half_as_ushort(__float2half_ru(x));
}

__global__ __launch_bounds__(256) void yolo_fused_kernel(
    const float* __restrict__ box_preds,   // [B,N,4]
    const float* __restrict__ cls_preds,   // [B,N,C]
    const float* __restrict__ gt_boxes,    // [B,M,4]
    const int*   __restrict__ gt_labels,   // [B,M]
    float4* __restrict__ partials,         // [nb] per-block {box,cls,npos,-}
    int N)
{
    const int b    = blockIdx.y;
    const int tid  = threadIdx.x;
    const int n    = blockIdx.x * 256 + tid;
    const int lane = tid & 63;
    const int wave = tid >> 6;

    __shared__ float4   sgt[M_GT];
    __shared__ uint2    spk[M_GT];   // conservative fp16 bits: {lo=(y1,x1)_rd, hi=(y2,x2)_ru|bias}
    __shared__ int      slbl[M_GT];
    __shared__ int      s_cnt;
    __shared__ unsigned plist[256];
    __shared__ float    redb[4], redc[4];

    if (tid == 0) s_cnt = 0;
    if (tid < M_GT) {
        float4 g = reinterpret_cast<const float4*>(gt_boxes + (size_t)b * M_GT * 4)[tid];
        sgt[tid]  = g;
        slbl[tid] = gt_labels[b * M_GT + tid];
        uint2 pk;
        pk.x = pack_rd(g.x, g.y);               // lo corner rounded down
        pk.y = pack_ru(g.z, g.w) | 0x80008000u; // hi corner rounded up, bias pre-OR'd
        spk[tid] = pk;
    }
    __syncthreads();

    const int nld = (n < N) ? n : (N - 1);
    float4 p = reinterpret_cast<const float4*>(box_preds + (size_t)b * N * 4)[nld];
    const float aw = p.z - p.x, ah = p.w - p.y, a1 = aw * ah;

    const unsigned P_lo    = pack_rd(p.x, p.y);
    const unsigned P_hi_or = pack_ru(p.z, p.w) | 0x80008000u;

    // ---- pass 1: conservative overlap masks, 2 GTs per ds_read_b128 ----
    // superset test px2>=gx1 & gx2>=px1 & py2>=gy1 & gy2>=py1 on fp16 bit patterns
    // (coords >= 0 so bit order == value order). Per-u16-half "a>=b" = bit15 of
    // (0x8000+a-b); halves can't borrow into each other since all values < 0x8000.
    const uint4* spk4 = reinterpret_cast<const uint4*>(spk);
    unsigned mk[4];
    #pragma unroll
    for (int q = 0; q < 4; ++q) {
        unsigned mm = 0;
        #pragma unroll 4
        for (int i = 0; i < 16; ++i) {
            uint4 w4 = spk4[q * 16 + i];      // {g0.lo, g0.hi|bias, g1.lo, g1.hi|bias}
            unsigned c0 = (P_hi_or - w4.x) & (w4.y - P_lo);
            unsigned c1 = (P_hi_or - w4.z) & (w4.w - P_lo);
            if ((c0 & 0x80008000u) == 0x80008000u) mm |= (1u << (2 * i));
            if ((c1 & 0x80008000u) == 0x80008000u) mm |= (1u << (2 * i + 1));
        }
        mk[q] = mm;
    }

    // ---- pass 2: exact fp32 GIoU over candidates (ascending order -> first-max kept) ----
    float best = -1e30f;   // tracks gip = giou + 1
    int   bidx = 0;
    #pragma unroll
    for (int q = 0; q < 4; ++q) {
        unsigned mm = mk[q];
        while (mm) {
            int t = __ffs(mm) - 1;
            mm &= mm - 1;
            int m = q * 32 + t;
            float4 g = sgt[m];
            float gw = g.z - g.x, gh = g.w - g.y, gA = gw * gh;
            float dx = fminf(p.z, g.z) - fmaxf(p.x, g.x);
            float dy = fminf(p.w, g.w) - fmaxf(p.y, g.y);
            float ex = (aw + gw) - dx;            // enclosure extents (identity, unclamped dx)
            float ey = (ah + gh) - dy;
            float inter = fmaxf(dx, 0.f) * fmaxf(dy, 0.f);   // clamp: mask may be dilated
            float uni = (a1 + gA) - inter;
            float ae  = ex * ey;
            // giou + 1 = (inter*ae + uni^2) / (uni*ae) — single reciprocal
            float gip = fmaf(uni, uni, inter * ae) * __builtin_amdgcn_rcpf(uni * ae);
            if (gip > best) { best = gip; bidx = m; }   // strict > keeps first idx
        }
    }
    // Exactness: positives (giou>0.3) have inter>0 with their argmax GT; the conservative
    // mask is a superset of overlapping GTs; dilation-extras have inter=0 -> gip<=1<1.3.

    bool  pos   = (n < N) && (best > 1.3f);     // giou > 0.3
    float box_l = pos ? (2.f - best) : 0.f;     // 1 - giou (elementwise giou == best)

    // ---- block-level compaction of positives ----
    {
        unsigned long long mkb = __ballot(pos);
        int cw = __popcll(mkb);
        if (cw > 0) {
            int leader = __ffsll(mkb) - 1;
            int base = 0;
            if (lane == leader) base = atomicAdd(&s_cnt, cw);   // LDS atomic
            base = __shfl(base, leader);
            if (pos) {
                int pre = __popcll(mkb & ((1ull << lane) - 1ull));
                plist[base + pre] = ((unsigned)slbl[bidx] << 18) | (unsigned)(b * N + n);
            }
        }
    }
    __syncthreads();

    // ---- focal over compacted positives (~17/block avg) ----
    const int cnt = s_cnt;
    float cls_l = 0.f;
    for (int i = tid; i < cnt; i += 256) {
        unsigned u = plist[i];
        int row = (int)(u & 0x3FFFFu);
        int lbl = (int)(u >> 18);
        const float* xrow = cls_preds + (size_t)row * NUM_CLASSES;
        float cl = 0.f;
        #pragma unroll 5
        for (int c4 = 0; c4 < NUM_CLASSES / 4; ++c4) {
            float4 xv = reinterpret_cast<const float4*>(xrow)[c4];
            cl += focal_neg(xv.x);
            cl += focal_neg(xv.y);
            cl += focal_neg(xv.z);
            cl += focal_neg(xv.w);
        }
        cl += focal_target_corr(xrow[lbl]);
        cls_l += cl;
    }

    // ---- block reduction, then ONE plain store per block (no global atomics) ----
    #pragma unroll
    for (int off = 32; off > 0; off >>= 1) {
        box_l += __shfl_down(box_l, off);
        cls_l += __shfl_down(cls_l, off);
    }
    if (lane == 0) { redb[wave] = box_l; redc[wave] = cls_l; }
    __syncthreads();
    if (tid == 0) {
        float b0 = redb[0] + redb[1] + redb[2] + redb[3];
        float c0 = redc[0] + redc[1] + redc[2] + redc[3];
        partials[blockIdx.y * gridDim.x + blockIdx.x] = make_float4(b0, c0, (float)cnt, 0.f);
    }
}

__global__ __launch_bounds__(256) void yolo_reduce(const float4* __restrict__ partials,
                                                   int nb, float* __restrict__ out) {
    const int tid = threadIdx.x;
    const int lane = tid & 63, wave = tid >> 6;
    double sb = 0.0, sc = 0.0, sp = 0.0;
    for (int i = tid; i < nb; i += 256) {
        float4 v = partials[i];
        sb += (double)v.x; sc += (double)v.y; sp += (double)v.z;
    }
    #pragma unroll
    for (int off = 32; off > 0; off >>= 1) {
        sb += __shfl_down(sb, off);
        sc += __shfl_down(sc, off);
        sp += __shfl_down(sp, off);
    }
    __shared__ double rb[4], rc[4], rp[4];
    if (lane == 0) { rb[wave] = sb; rc[wave] = sc; rp[wave] = sp; }
    __syncthreads();
    if (tid == 0) {
        double B0 = rb[0] + rb[1] + rb[2] + rb[3];
        double C0 = rc[0] + rc[1] + rc[2] + rc[3];
        double P0 = rp[0] + rp[1] + rp[2] + rp[3];
        out[0] = (float)((5.0 * B0 + C0) / fmax(P0, 1.0));
    }
}

extern "C" void kernel_launch(void* const* d_in, const int* in_sizes, int n_in,
                              void* d_out, int out_size, void* d_ws, size_t ws_size,
                              hipStream_t stream) {
    const float* box_preds = (const float*)d_in[0];
    const float* cls_preds = (const float*)d_in[1];
    const float* gt_boxes  = (const float*)d_in[2];
    const int*   gt_labels = (const int*)d_in[3];

    const int B = in_sizes[3] / M_GT;            // gt_labels is [B,M]
    const int N = in_sizes[0] / (4 * B);         // box_preds is [B,N,4]

    float4* partials = (float4*)d_ws;
    float*  out      = (float*)d_out;

    const int gx = (N + 255) / 256;
    dim3 grid(gx, B);
    yolo_fused_kernel<<<grid, 256, 0, stream>>>(box_preds, cls_preds, gt_boxes,
                                                gt_labels, partials, N);

    yolo_reduce<<<1, 256, 0, stream>>>(partials, gx * B, out);
}